// Round 3
// baseline (3613.400 us; speedup 1.0000x reference)
//
#include <hip/hip_runtime.h>

#define B_SZ   256
#define T_SZ   1000
#define N_IN   128
#define UNITS  512

// ---------------------------------------------------------------------------
// Phase 1: C[M,512] = X[M,128] @ W[128,512],  M = B*T = 256000, fp32.
// (unchanged — measured at ~fp32 vector roofline, ~210 us)
// ---------------------------------------------------------------------------
__global__ __launch_bounds__(256) void gemm_in(const float* __restrict__ X,
                                               const float* __restrict__ W,
                                               float* __restrict__ C) {
    __shared__ __align__(16) float As[32][128];  // As[k][m] (transposed x tile)
    __shared__ __align__(16) float Bs[32][128];  // Bs[k][n]

    const int tid = threadIdx.x;
    const int ntile = blockIdx.x & 3;        // 512/128 = 4 n-tiles
    const int mtile = blockIdx.x >> 2;       // 2000 m-tiles
    const int m0 = mtile * 128, n0 = ntile * 128;
    const int tm  = (tid >> 4) * 8;          // 16 m-groups of 8
    const int tn4 = (tid & 15) * 4;          // 16 n-groups of 4 (+ mirror at +64)

    float acc[8][8];
#pragma unroll
    for (int i = 0; i < 8; ++i)
#pragma unroll
        for (int j = 0; j < 8; ++j) acc[i][j] = 0.0f;

    for (int k0 = 0; k0 < 128; k0 += 32) {
        __syncthreads();
#pragma unroll
        for (int r = 0; r < 4; ++r) {
            int li  = r * 256 + tid;          // 0..1023 float4 slots
            int row = li >> 3;                // 0..127
            int ch  = li & 7;                 // 0..7 (4 floats each)
            float4 a = *(const float4*)&X[(size_t)(m0 + row) * 128 + k0 + ch * 4];
            As[ch * 4 + 0][row] = a.x;
            As[ch * 4 + 1][row] = a.y;
            As[ch * 4 + 2][row] = a.z;
            As[ch * 4 + 3][row] = a.w;
        }
#pragma unroll
        for (int r = 0; r < 4; ++r) {
            int li = r * 256 + tid;
            int kk = li >> 5;                 // 0..31
            int n4 = li & 31;                 // 0..31
            *(float4*)&Bs[kk][n4 * 4] =
                *(const float4*)&W[(size_t)(k0 + kk) * 512 + n0 + n4 * 4];
        }
        __syncthreads();

#pragma unroll 8
        for (int k = 0; k < 32; ++k) {
            float4 a0 = *(const float4*)&As[k][tm];
            float4 a1 = *(const float4*)&As[k][tm + 4];
            float4 b0 = *(const float4*)&Bs[k][tn4];
            float4 b1 = *(const float4*)&Bs[k][tn4 + 64];
            const float av[8] = {a0.x, a0.y, a0.z, a0.w, a1.x, a1.y, a1.z, a1.w};
            const float bv[8] = {b0.x, b0.y, b0.z, b0.w, b1.x, b1.y, b1.z, b1.w};
#pragma unroll
            for (int i = 0; i < 8; ++i)
#pragma unroll
                for (int j = 0; j < 8; ++j)
                    acc[i][j] = fmaf(av[i], bv[j], acc[i][j]);
        }
    }

#pragma unroll
    for (int i = 0; i < 8; ++i) {
        size_t row = (size_t)(m0 + tm + i) * 512;
        float4 c0 = make_float4(acc[i][0], acc[i][1], acc[i][2], acc[i][3]);
        float4 c1 = make_float4(acc[i][4], acc[i][5], acc[i][6], acc[i][7]);
        *(float4*)&C[row + n0 + tn4]      = c0;
        *(float4*)&C[row + n0 + 64 + tn4] = c1;
    }
}

// ---------------------------------------------------------------------------
// Phase 2: ALIF scan, wide-window sparse i_rec.
// One WG per batch row (256 WGs x 512 threads), thread u owns unit u.
// Per step: read up to 64 active indices in ONE burst (16x ds_read_b128, all
// independent), issue all 64 W_rec gathers concurrently (one L2 round-trip
// paid per chunk, not per 8-group), then a single predicated ascending
// __fadd_rn chain — bit-identical accumulation order to the passing r1/r2
// kernels (padded entries predicated to exact +0.0f).
// No stage rotation => no v_mov overhead (the r2 mistake).
// VGPR ~150 is free here: grid = 1 block/CU, <=256 VGPR keeps 2 waves/SIMD.
// ---------------------------------------------------------------------------
__global__ __launch_bounds__(512, 2) void alif_scan(const float* __restrict__ Wr,
                                                    float* __restrict__ IO) {
    const int b = blockIdx.x;
    const int u = threadIdx.x;
    const int w = u >> 6;                    // wave id (0..7)
    const int lane = u & 63;

    __shared__ __align__(16) int s_list[576];  // 512 + 64 pad (idx 0)
    __shared__ int s_cnt[8];
    __shared__ int s_total;

    const float DECAY   = 0.95122942450071400910f;   // exp(-1/20)
    const float OMD     = 1.0f - DECAY;
    const float DECAY_B = 0.99501247919268232342f;   // exp(-1/200)
    const float OMDB    = 1.0f - DECAY_B;

    float v = 0.0f, ad = 0.0f, z = 0.0f;

    const float* wcol = Wr + u;                       // column u of W_rec
    float* io = IO + (size_t)b * (T_SZ * UNITS) + u;  // [t][u] slab for batch b

    if (u == 0) s_total = 0;
    __syncthreads();

    float i_cur = io[0];

    for (int t = 0; t < T_SZ; ++t) {
        // prefetch next step's input current (~1000 cyc ahead of its use)
        float i_next = io[(t + 1 < T_SZ ? t + 1 : t) * UNITS];

        const int cnt = s_total;
        float acc = 0.0f;

        for (int c0 = 0; c0 < cnt; c0 += 64) {
            // 1) one burst of index reads (16 independent ds_read_b128)
            int4 I[16];
#pragma unroll
            for (int r = 0; r < 16; ++r)
                I[r] = *(const int4*)(s_list + c0 + 4 * r);
            // 2) all 64 gathers issued together (concurrent L2 round-trip)
            float G[64];
#pragma unroll
            for (int r = 0; r < 16; ++r) {
                G[4 * r + 0] = wcol[I[r].x * UNITS];
                G[4 * r + 1] = wcol[I[r].y * UNITS];
                G[4 * r + 2] = wcol[I[r].z * UNITS];
                G[4 * r + 3] = wcol[I[r].w * UNITS];
            }
            // 3) strictly ascending predicated add chain (exact order)
#pragma unroll
            for (int r = 0; r < 16; ++r) {
                const int base = c0 + 4 * r;
                acc = __fadd_rn(acc, (base + 0 < cnt && I[r].x != u) ? G[4 * r + 0] : 0.0f);
                acc = __fadd_rn(acc, (base + 1 < cnt && I[r].y != u) ? G[4 * r + 1] : 0.0f);
                acc = __fadd_rn(acc, (base + 2 < cnt && I[r].z != u) ? G[4 * r + 2] : 0.0f);
                acc = __fadd_rn(acc, (base + 3 < cnt && I[r].w != u) ? G[4 * r + 3] : 0.0f);
            }
        }

        // elementwise state update — exact reference op order, no contraction
        float newb = __fadd_rn(__fmul_rn(DECAY_B, ad), __fmul_rn(OMDB, z));
        float thr  = __fadd_rn(0.01f, __fmul_rn(newb, 1.6f));
        float it   = __fadd_rn(__fadd_rn(i_cur, acc), 0.0f);       // + ADD_CUR
        float ires = __fmul_rn(__fmul_rn(z, thr), 1.0f);           // * DT
        float newv = __fsub_rn(
            __fadd_rn(__fmul_rn(DECAY, v), __fmul_rn(OMD, it)), ires);
        float zn = (newv > thr) ? 1.0f : 0.0f;      // refractory is a no-op

        io[t * UNITS] = zn;                          // overwrite i_in with z
        v = newv; ad = newb; z = zn; i_cur = i_next;

        // rebuild active list for next step (deterministic ascending order)
        unsigned long long m = __ballot(zn > 0.0f);
        if (lane == 0) s_cnt[w] = __popcll(m);
        __syncthreads();   // [A] all waves done reading old list; cnts visible

        int base = 0, total = 0;
#pragma unroll
        for (int i = 0; i < 8; ++i) {
            int c = s_cnt[i];
            total += c;
            if (i < w) base += c;
        }
        if (zn > 0.0f) {
            int pos = base + __popcll(m & ((1ull << lane) - 1ull));
            s_list[pos] = u;
        }
        if (u == 0) s_total = total;
        if (u < 64) s_list[total + u] = 0;           // pad for 64-wide reads
        __syncthreads();   // [C] list ready
    }
}

extern "C" void kernel_launch(void* const* d_in, const int* in_sizes, int n_in,
                              void* d_out, int out_size, void* d_ws, size_t ws_size,
                              hipStream_t stream) {
    (void)in_sizes; (void)n_in; (void)out_size; (void)d_ws; (void)ws_size;
    const float* x     = (const float*)d_in[0];   // [B,T,128]
    const float* W_in  = (const float*)d_in[1];   // [128,512]
    const float* W_rec = (const float*)d_in[2];   // [512,512]
    float* out = (float*)d_out;                   // [B,T,512]

    gemm_in<<<dim3((B_SZ * T_SZ / 128) * (UNITS / 128)), dim3(256), 0, stream>>>(
        x, W_in, out);
    alif_scan<<<dim3(B_SZ), dim3(512), 0, stream>>>(W_rec, out);
}

// Round 4
// 2981.748 us; speedup vs baseline: 1.2118x; 1.2118x over previous
//
#include <hip/hip_runtime.h>

#define B_SZ   256
#define T_SZ   1000
#define N_IN   128
#define UNITS  512
#define NC     64        // rows of W_rec cached in LDS (wave-0's units)

// dynamic LDS layout (bytes):
//   [0, 131072)            float lds_w[64][512]   (rows 0..63, diag zeroed)
//   [131072, 133120)       int   list0[512]       (segmented active list, buf 0)
//   [133120, 135168)       int   list1[512]       (buf 1)
//   [135168, 135200)       int   cnt0[8]
//   [135200, 135232)       int   cnt1[8]
#define SMEM_BYTES 135232

// ---------------------------------------------------------------------------
// Phase 1: C[M,512] = X[M,128] @ W[128,512],  M = B*T = 256000, fp32.
// (unchanged — measured at ~fp32 vector roofline, ~210 us)
// ---------------------------------------------------------------------------
__global__ __launch_bounds__(256) void gemm_in(const float* __restrict__ X,
                                               const float* __restrict__ W,
                                               float* __restrict__ C) {
    __shared__ __align__(16) float As[32][128];  // As[k][m] (transposed x tile)
    __shared__ __align__(16) float Bs[32][128];  // Bs[k][n]

    const int tid = threadIdx.x;
    const int ntile = blockIdx.x & 3;        // 512/128 = 4 n-tiles
    const int mtile = blockIdx.x >> 2;       // 2000 m-tiles
    const int m0 = mtile * 128, n0 = ntile * 128;
    const int tm  = (tid >> 4) * 8;          // 16 m-groups of 8
    const int tn4 = (tid & 15) * 4;          // 16 n-groups of 4 (+ mirror at +64)

    float acc[8][8];
#pragma unroll
    for (int i = 0; i < 8; ++i)
#pragma unroll
        for (int j = 0; j < 8; ++j) acc[i][j] = 0.0f;

    for (int k0 = 0; k0 < 128; k0 += 32) {
        __syncthreads();
#pragma unroll
        for (int r = 0; r < 4; ++r) {
            int li  = r * 256 + tid;          // 0..1023 float4 slots
            int row = li >> 3;                // 0..127
            int ch  = li & 7;                 // 0..7 (4 floats each)
            float4 a = *(const float4*)&X[(size_t)(m0 + row) * 128 + k0 + ch * 4];
            As[ch * 4 + 0][row] = a.x;
            As[ch * 4 + 1][row] = a.y;
            As[ch * 4 + 2][row] = a.z;
            As[ch * 4 + 3][row] = a.w;
        }
#pragma unroll
        for (int r = 0; r < 4; ++r) {
            int li = r * 256 + tid;
            int kk = li >> 5;                 // 0..31
            int n4 = li & 31;                 // 0..31
            *(float4*)&Bs[kk][n4 * 4] =
                *(const float4*)&W[(size_t)(k0 + kk) * 512 + n0 + n4 * 4];
        }
        __syncthreads();

#pragma unroll 8
        for (int k = 0; k < 32; ++k) {
            float4 a0 = *(const float4*)&As[k][tm];
            float4 a1 = *(const float4*)&As[k][tm + 4];
            float4 b0 = *(const float4*)&Bs[k][tn4];
            float4 b1 = *(const float4*)&Bs[k][tn4 + 64];
            const float av[8] = {a0.x, a0.y, a0.z, a0.w, a1.x, a1.y, a1.z, a1.w};
            const float bv[8] = {b0.x, b0.y, b0.z, b0.w, b1.x, b1.y, b1.z, b1.w};
#pragma unroll
            for (int i = 0; i < 8; ++i)
#pragma unroll
                for (int j = 0; j < 8; ++j)
                    acc[i][j] = fmaf(av[i], bv[j], acc[i][j]);
        }
    }

#pragma unroll
    for (int i = 0; i < 8; ++i) {
        size_t row = (size_t)(m0 + tm + i) * 512;
        float4 c0 = make_float4(acc[i][0], acc[i][1], acc[i][2], acc[i][3]);
        float4 c1 = make_float4(acc[i][4], acc[i][5], acc[i][6], acc[i][7]);
        *(float4*)&C[row + n0 + tn4]      = c0;
        *(float4*)&C[row + n0 + 64 + tn4] = c1;
    }
}

// ---------------------------------------------------------------------------
// Phase 2: ALIF scan. One WG per batch (256 WGs x 512 threads), thread u
// owns unit u. L2-BW-bound => cut traffic:
//  - rows 0..63 of W_rec live in LDS (staged once, diag pre-zeroed): active
//    j<64 cost no L2 traffic (~12.5% cut).
//  - segmented, double-buffered active list: wave w's actives in slots
//    [w*64, w*64+cnt_w), built with no cross-wave prefix; ONE barrier/step.
//    Read order seg0..seg7 (ascending within) == globally ascending j, so the
//    __fadd_rn chain is bit-identical to the passing r1 kernel. Stale entries
//    past cnt_w are old same-wave ids (legal rows) predicated to exact +0.0f.
//  - global gathers keep r1's 8-in-flight group pattern.
// ---------------------------------------------------------------------------
__global__ __launch_bounds__(512, 2) void alif_scan(const float* __restrict__ Wr,
                                                    float* __restrict__ IO) {
    extern __shared__ __align__(16) float smem[];
    float* lds_w   = smem;                       // [64][512]
    int*   listbuf = (int*)(smem + NC * UNITS);  // [2][512]
    int*   cntbuf  = listbuf + 2 * UNITS;        // [2][8]

    const int b = blockIdx.x;
    const int u = threadIdx.x;
    const int w = u >> 6;                    // wave id (0..7)
    const int lane = u & 63;

    const float DECAY   = 0.95122942450071400910f;   // exp(-1/20)
    const float OMD     = 1.0f - DECAY;
    const float DECAY_B = 0.99501247919268232342f;   // exp(-1/200)
    const float OMDB    = 1.0f - DECAY_B;

    float v = 0.0f, ad = 0.0f, z = 0.0f;

    const float* wcol = Wr + u;                       // column u of W_rec
    float* io = IO + (size_t)b * (T_SZ * UNITS) + u;  // [t][u] slab for batch b

    // ---- one-time init: zero lists/counts, stage W_rec rows 0..63 ----
    listbuf[u] = 0;
    listbuf[UNITS + u] = 0;
    if (u < 16) cntbuf[u] = 0;
#pragma unroll 4
    for (int j = 0; j < NC; ++j)
        lds_w[j * UNITS + u] = (j == u) ? 0.0f : Wr[(size_t)j * UNITS + u];
    __syncthreads();

    float i_cur = io[0];

    for (int t = 0; t < T_SZ; ++t) {
        const int cur = t & 1, nxt = cur ^ 1;
        const int* list = listbuf + cur * UNITS;
        const int* cnts = cntbuf + cur * 8;

        // prefetch next step's input current
        float i_next = io[(t + 1 < T_SZ ? t + 1 : t) * UNITS];

        int4 cA = *(const int4*)(cnts);      // counts for waves 0..3
        int4 cB = *(const int4*)(cnts + 4);  // counts for waves 4..7
        const int cw[8] = {cA.x, cA.y, cA.z, cA.w, cB.x, cB.y, cB.z, cB.w};

        float acc = 0.0f;

        // ---- segment 0: units 0..63 from LDS (no L2 traffic) ----
        {
            const int c0 = cw[0];
            for (int k = 0; k < c0; k += 4) {
                int4 J = *(const int4*)(list + k);   // stale-safe: ids in [0,64)
                float g0 = lds_w[J.x * UNITS + u];
                float g1 = lds_w[J.y * UNITS + u];
                float g2 = lds_w[J.z * UNITS + u];
                float g3 = lds_w[J.w * UNITS + u];
                acc = __fadd_rn(acc, (k + 0 < c0) ? g0 : 0.0f);
                acc = __fadd_rn(acc, (k + 1 < c0) ? g1 : 0.0f);
                acc = __fadd_rn(acc, (k + 2 < c0) ? g2 : 0.0f);
                acc = __fadd_rn(acc, (k + 3 < c0) ? g3 : 0.0f);
            }
        }

        // ---- segments 1..7: L2 gathers, 8 loads in flight (r1 pattern) ----
        for (int ws = 1; ws < 8; ++ws) {
            const int c = cw[ws];
            const int* seg = list + ws * 64;
            for (int k = 0; k < c; k += 8) {
                int4 Ja = *(const int4*)(seg + k);
                int4 Jb = *(const int4*)(seg + k + 4);
                float g0 = wcol[Ja.x * UNITS];
                float g1 = wcol[Ja.y * UNITS];
                float g2 = wcol[Ja.z * UNITS];
                float g3 = wcol[Ja.w * UNITS];
                float g4 = wcol[Jb.x * UNITS];
                float g5 = wcol[Jb.y * UNITS];
                float g6 = wcol[Jb.z * UNITS];
                float g7 = wcol[Jb.w * UNITS];
                acc = __fadd_rn(acc, (k + 0 < c && Ja.x != u) ? g0 : 0.0f);
                acc = __fadd_rn(acc, (k + 1 < c && Ja.y != u) ? g1 : 0.0f);
                acc = __fadd_rn(acc, (k + 2 < c && Ja.z != u) ? g2 : 0.0f);
                acc = __fadd_rn(acc, (k + 3 < c && Ja.w != u) ? g3 : 0.0f);
                acc = __fadd_rn(acc, (k + 4 < c && Jb.x != u) ? g4 : 0.0f);
                acc = __fadd_rn(acc, (k + 5 < c && Jb.y != u) ? g5 : 0.0f);
                acc = __fadd_rn(acc, (k + 6 < c && Jb.z != u) ? g6 : 0.0f);
                acc = __fadd_rn(acc, (k + 7 < c && Jb.w != u) ? g7 : 0.0f);
            }
        }

        // ---- elementwise state update — exact reference op order ----
        float newb = __fadd_rn(__fmul_rn(DECAY_B, ad), __fmul_rn(OMDB, z));
        float thr  = __fadd_rn(0.01f, __fmul_rn(newb, 1.6f));
        float it   = __fadd_rn(__fadd_rn(i_cur, acc), 0.0f);       // + ADD_CUR
        float ires = __fmul_rn(__fmul_rn(z, thr), 1.0f);           // * DT
        float newv = __fsub_rn(
            __fadd_rn(__fmul_rn(DECAY, v), __fmul_rn(OMD, it)), ires);
        float zn = (newv > thr) ? 1.0f : 0.0f;      // refractory is a no-op

        io[t * UNITS] = zn;                          // overwrite i_in with z
        v = newv; ad = newb; z = zn; i_cur = i_next;

        // ---- rebuild active list into the OTHER buffer; one barrier ----
        unsigned long long m = __ballot(zn > 0.0f);
        if (lane == 0) cntbuf[nxt * 8 + w] = __popcll(m);
        if (zn > 0.0f) {
            int pos = __popcll(m & ((1ull << lane) - 1ull));
            listbuf[nxt * UNITS + w * 64 + pos] = u;
        }
        __syncthreads();   // new list/counts ready; old buffer free for reuse
    }
}

extern "C" void kernel_launch(void* const* d_in, const int* in_sizes, int n_in,
                              void* d_out, int out_size, void* d_ws, size_t ws_size,
                              hipStream_t stream) {
    (void)in_sizes; (void)n_in; (void)out_size; (void)d_ws; (void)ws_size;
    const float* x     = (const float*)d_in[0];   // [B,T,128]
    const float* W_in  = (const float*)d_in[1];   // [128,512]
    const float* W_rec = (const float*)d_in[2];   // [512,512]
    float* out = (float*)d_out;                   // [B,T,512]

    gemm_in<<<dim3((B_SZ * T_SZ / 128) * (UNITS / 128)), dim3(256), 0, stream>>>(
        x, W_in, out);

    // allow >64KB dynamic LDS (host-side, capture-safe, idempotent)
    hipFuncSetAttribute((const void*)alif_scan,
                        hipFuncAttributeMaxDynamicSharedMemorySize, SMEM_BYTES);
    alif_scan<<<dim3(B_SZ), dim3(512), SMEM_BYTES, stream>>>(W_rec, out);
}